// Round 11
// baseline (187.496 us; speedup 1.0000x reference)
//
#include <hip/hip_runtime.h>
#include <hip/hip_bf16.h>

#define H_IMG 224
#define W_IMG 224
#define B_ 4
#define C_ 256
#define M_ 1024
#define N_ 16384
#define HW_ (H_IMG * W_IMG)
#define OH_ 56
#define OW_ 56
#define NBLK_ (OH_ * OW_)        // 3136 pool blocks per batch
#define NBINS_ (B_ * NBLK_)      // 12544 total bins
#define NT_ (B_ * N_)            // 65536 total points
#define SEG_ 32                  // max points per gather segment
#define MAXSEG_ (NBINS_ + NT_ / SEG_)   // 14592 upper bound
#define KS_ 8                    // center-dimension slices in top3
#define MC_ (M_ / KS_)           // 128 centers per slice
// contiguous zero region: tmp + cnt + binCnt + binFill + segTotal
#define ZTOT_ (NBINS_ * C_ + B_ * HW_ + 2 * NBINS_ + 1)

// ------- Kernel A: transpose xyz_feats (B,C,M)->XT (B,M,C) + fused zeroing -
__global__ __launch_bounds__(1024) void transpose_kernel(
    const float* __restrict__ xyz, float* __restrict__ XT,
    float* __restrict__ zeroRegion)
{
    __shared__ float tile[32][33];
    int b  = blockIdx.z;
    int c0 = blockIdx.x * 32;
    int m0 = blockIdx.y * 32;
    int tx = threadIdx.x, ty = threadIdx.y;
    // fused zeroing (replaces memsets): 1,048,576 threads cover ZTOT_
    int flat = ((blockIdx.z * gridDim.y + blockIdx.y) * gridDim.x + blockIdx.x)
               * 1024 + ty * 32 + tx;
    for (int i = flat; i < ZTOT_; i += 1024 * 1024) zeroRegion[i] = 0.0f;
    tile[ty][tx] = xyz[(b * C_ + c0 + ty) * M_ + m0 + tx];
    __syncthreads();
    XT[(b * M_ + m0 + ty) * C_ + c0 + tx] = tile[tx][ty];
}

// -------- Kernel B: top-3 NN, 8 K-slices x 128 lanes, 2 points per thread --
// NUMERICS LOCKED (R7 pass): np ref einsum tail is DESCENDING-index separate
// mul/add: dot = ((pz*cz)+(py*cy))+(px*cx); p2/c2 ascending; d=(p2+c2)-2*dot;
// contract(off); stable top-3 (lowest index on exact ties); projection
// order-invariant. DO NOT change any decision arithmetic.
// R10 postmortem: VALUBusy-derived ~42 lane-ops/center (if-converted insert
// paid every iter + per-iter overhead at 1 center/thread). v3: each thread
// scans 128 centers for TWO points sharing one cen[m] broadcast read ->
// halves per-point overhead, doubles ILP; occupancy unchanged (256 blocks,
// 16 waves/CU). Per-slice strict-< insert (lex-sorted by (d,idx)) + lex
// merge of 8x3 candidates == global stable top-3 (same proof as R10).
__global__ __launch_bounds__(1024) void top3_kernel(
    const float* __restrict__ points, const float* __restrict__ centers,
    const float* __restrict__ Kmat,
    int* __restrict__ pixA, int* __restrict__ idA, float* __restrict__ wA,
    float* __restrict__ cnt, int* __restrict__ binCnt)
{
#pragma clang fp contract(off)
    __shared__ float4 cen[M_];           // 16 KB
    __shared__ float  pd[KS_][256][3];   // 24 KB partial distances
    __shared__ int    pi[KS_][256][3];   // 24 KB partial indices
    int b  = blockIdx.y;
    int t  = threadIdx.x;
    int pl = t & 127;                    // point lane
    int s  = t >> 7;                     // slice
    int nbase = blockIdx.x * 256;

    {   // stage centers: one per thread (t in [0,1024) == M_)
        float cx = centers[(b * M_ + t) * 3 + 0];
        float cy = centers[(b * M_ + t) * 3 + 1];
        float cz = centers[(b * M_ + t) * 3 + 2];
        float c2 = ((cx * cx) + (cy * cy)) + (cz * cz);  // np.sum ascending
        cen[t] = make_float4(cx, cy, cz, c2);
    }
    __syncthreads();

    int nA = b * N_ + nbase + pl;        // point A: local pl
    int nB = nA + 128;                   // point B: local pl+128
    float pxA = points[nA * 3 + 0], pyA = points[nA * 3 + 1], pzA = points[nA * 3 + 2];
    float pxB = points[nB * 3 + 0], pyB = points[nB * 3 + 1], pzB = points[nB * 3 + 2];
    float p2A = ((pxA * pxA) + (pyA * pyA)) + (pzA * pzA);   // np.sum ascending
    float p2B = ((pxB * pxB) + (pyB * pyB)) + (pzB * pzB);

    float d0a = 1e30f, d1a = 1e30f, d2a = 1e30f;
    int   i0a = 0, i1a = 0, i2a = 0;
    float d0b = 1e30f, d1b = 1e30f, d2b = 1e30f;
    int   i0b = 0, i1b = 0, i2b = 0;
    int mbase = s * MC_;
#pragma unroll 2
    for (int j = 0; j < MC_; ++j) {
        int m = mbase + j;
        float4 cc = cen[m];               // uniform in wave: LDS broadcast
        float dotA = ((pzA * cc.z) + (pyA * cc.y)) + (pxA * cc.x); // np tail
        float dA   = (p2A + cc.w) - (2.0f * dotA);
        float dotB = ((pzB * cc.z) + (pyB * cc.y)) + (pxB * cc.x);
        float dB   = (p2B + cc.w) - (2.0f * dotB);
        if (dA < d2a) {                   // strict <: lowest index on ties
            if (dA < d1a) {
                d2a = d1a; i2a = i1a;
                if (dA < d0a) { d1a = d0a; i1a = i0a; d0a = dA; i0a = m; }
                else          { d1a = dA;  i1a = m; }
            } else { d2a = dA; i2a = m; }
        }
        if (dB < d2b) {
            if (dB < d1b) {
                d2b = d1b; i2b = i1b;
                if (dB < d0b) { d1b = d0b; i1b = i0b; d0b = dB; i0b = m; }
                else          { d1b = dB;  i1b = m; }
            } else { d2b = dB; i2b = m; }
        }
    }
    pd[s][pl][0] = d0a;  pd[s][pl][1] = d1a;  pd[s][pl][2] = d2a;
    pi[s][pl][0] = i0a;  pi[s][pl][1] = i1a;  pi[s][pl][2] = i2a;
    pd[s][pl + 128][0] = d0b;  pd[s][pl + 128][1] = d1b;  pd[s][pl + 128][2] = d2b;
    pi[s][pl + 128][0] = i0b;  pi[s][pl + 128][1] = i1b;  pi[s][pl + 128][2] = i2b;
    __syncthreads();

    if (t < 256) {
        // merge 24 candidates, full lexicographic (d, idx): order-independent
        float md0 = 1e30f, md1 = 1e30f, md2 = 1e30f;
        int   mi0 = M_,    mi1 = M_,    mi2 = M_;
#pragma unroll
        for (int ss = 0; ss < KS_; ++ss)
#pragma unroll
            for (int j = 0; j < 3; ++j) {
                float dd = pd[ss][t][j];
                int   ii = pi[ss][t][j];
                if ((dd < md2) || (dd == md2 && ii < mi2)) {
                    if ((dd < md1) || (dd == md1 && ii < mi1)) {
                        md2 = md1; mi2 = mi1;
                        if ((dd < md0) || (dd == md0 && ii < mi0)) {
                            md1 = md0; mi1 = mi0; md0 = dd; mi0 = ii;
                        } else { md1 = dd; mi1 = ii; }
                    } else { md2 = dd; mi2 = ii; }
                }
            }

        float w0 = 1.0f / (md0 + 1e-8f);
        float w1 = 1.0f / (md1 + 1e-8f);
        float w2 = 1.0f / (md2 + 1e-8f);
        float ws = (w0 + w1) + w2;
        w0 /= ws; w1 /= ws; w2 /= ws;

        // reload this point's coords (L1-hot)
        int n = nbase + t;
        int g = b * N_ + n;
        float px = points[g * 3 + 0], py = points[g * 3 + 1], pz = points[g * 3 + 2];

        // projection: order-invariant (single add of two products; 0*py exact)
        float fx = Kmat[0], cxk = Kmat[2], fy = Kmat[4], cyk = Kmat[5];
        float u_num = (cxk * pz) + (fx * px);
        float v_num = (cyk * pz) + (fy * py);
        float zc    = fmaxf(pz, 1e-8f);
        float u = floorf(u_num / zc);
        float v = floorf(v_num / zc);
        int ui = (int)fminf(fmaxf(u, 0.0f), (float)(W_IMG - 1));
        int vi = (int)fminf(fmaxf(v, 0.0f), (float)(H_IMG - 1));
        int pix = vi * W_IMG + ui;

        pixA[g] = pix;
        idA[g]           = mi0; idA[g + NT_]     = mi1; idA[g + 2 * NT_] = mi2;
        wA [g]           = w0;  wA [g + NT_]     = w1;  wA [g + 2 * NT_] = w2;
        atomicAdd(&cnt[b * HW_ + pix], 1.0f);
        int bin = b * NBLK_ + (vi >> 2) * OW_ + (ui >> 2);
        atomicAdd(&binCnt[bin], 1);
    }
}

// ------- Kernel S: dual exclusive scan (k, nseg) + deterministic seg emit --
// Fuses R10's segbuild: segBase = prefix-sum of nseg, no atomic counter,
// one fewer dispatch, deterministic segment order.
__global__ __launch_bounds__(1024) void scan_kernel(
    const int* __restrict__ binCnt, int* __restrict__ binOff,
    int4* __restrict__ segs, int* __restrict__ segTotal)
{
    const int PER = (NBINS_ + 1023) / 1024;   // 13
    __shared__ int partK[1024], partS[1024];
    int t = threadIdx.x;
    int base = t * PER;
    int localK[PER], localS[PER];
    int sk = 0, sn = 0;
#pragma unroll
    for (int j = 0; j < PER; ++j) {
        int idx = base + j;
        int k  = (idx < NBINS_) ? binCnt[idx] : 0;
        int ns = 0;
        if (idx < NBINS_) { ns = (k + SEG_ - 1) / SEG_; if (ns == 0) ns = 1; }
        localK[j] = sk; localS[j] = sn;
        sk += k; sn += ns;
    }
    partK[t] = sk; partS[t] = sn;
    __syncthreads();
    for (int ofs = 1; ofs < 1024; ofs <<= 1) {
        int vK = (t >= ofs) ? partK[t - ofs] : 0;
        int vS = (t >= ofs) ? partS[t - ofs] : 0;
        __syncthreads();
        partK[t] += vK; partS[t] += vS;
        __syncthreads();
    }
    int exK = (t == 0) ? 0 : partK[t - 1];
    int exS = (t == 0) ? 0 : partS[t - 1];
#pragma unroll
    for (int j = 0; j < PER; ++j) {
        int idx = base + j;
        if (idx >= NBINS_) continue;
        int off = exK + localK[j];
        int sb  = exS + localS[j];
        binOff[idx] = off;
        int k = binCnt[idx];
        int nseg = (k + SEG_ - 1) / SEG_; if (nseg == 0) nseg = 1;
        for (int q = 0; q < nseg; ++q) {
            int len = k - q * SEG_;
            len = (len < 0) ? 0 : ((len > SEG_) ? SEG_ : len);
            segs[sb + q] = make_int4(idx, off + q * SEG_, len, nseg);
        }
    }
    if (t == 0) segTotal[0] = partS[1023];
}

// ---------------- Kernel P: pack points into bin order, pre-scale weights --
__global__ __launch_bounds__(256) void pack_kernel(
    const int* __restrict__ pixA, const int* __restrict__ idA,
    const float* __restrict__ wA, const float* __restrict__ cnt,
    const int* __restrict__ binOff, int* __restrict__ binFill,
    int4* __restrict__ idP, float4* __restrict__ wP)
{
    int g = blockIdx.x * 256 + threadIdx.x;
    int b = g >> 14;                     // N_ = 16384
    int pix = pixA[g];
    int u = pix % W_IMG, v = pix / W_IMG;
    int bin = b * NBLK_ + (v >> 2) * OW_ + (u >> 2);
    int pos = atomicAdd(&binFill[bin], 1);
    int dst = binOff[bin] + pos;
    float s = 0.0625f / fmaxf(cnt[b * HW_ + pix], 1.0f);
    idP[dst] = make_int4(idA[g], idA[g + NT_], idA[g + 2 * NT_], b);
    wP[dst]  = make_float4(wA[g] * s, wA[g + NT_] * s, wA[g + 2 * NT_] * s, 0.0f);
}

// ---------------- Kernel G: per-segment gather-reduce into bin-major tmp ---
// Bin-major stores: 64 consecutive lanes = contiguous 1KB => zero inflation.
__global__ __launch_bounds__(256) void gather_kernel(
    const float* __restrict__ XT, const int4* __restrict__ segs,
    const int* __restrict__ segTotal, const int4* __restrict__ idP,
    const float4* __restrict__ wP, float* __restrict__ tmp)
{
    int sid = blockIdx.x;
    if (sid >= segTotal[0]) return;
    int4 sg   = segs[sid];
    int bin   = sg.x, start = sg.y, len = sg.z, nseg = sg.w;
    int b     = bin / NBLK_;
    int c     = threadIdx.x;

    __shared__ int4   sId[SEG_];
    __shared__ float4 sW [SEG_];
    if (c < len) { sId[c] = idP[start + c]; sW[c] = wP[start + c]; }
    __syncthreads();

    const float* XTb = XT + (size_t)b * (M_ * C_);
    float acc = 0.0f;
    for (int j = 0; j < len; ++j) {
        int4   id = sId[j];               // LDS broadcast
        float4 w  = sW[j];
        acc = fmaf(w.x, XTb[id.x * C_ + c],
              fmaf(w.y, XTb[id.y * C_ + c],
              fmaf(w.z, XTb[id.z * C_ + c], acc)));
    }

    float* dst = &tmp[(size_t)bin * C_ + c];
    if (nseg == 1) *dst = acc;            // covers empty bins (acc = 0)
    else           atomicAdd(dst, acc);   // tmp pre-zeroed in transpose_kernel
}

// ---------------- Kernel U: untranspose tmp (B,NBLK,C) -> out (B,C,NBLK) ---
__global__ __launch_bounds__(1024) void untranspose_kernel(
    const float* __restrict__ tmp, float* __restrict__ out)
{
    __shared__ float tile[32][33];
    int b  = blockIdx.z;
    int n0 = blockIdx.x * 32;   // NBLK_/32 = 98
    int c0 = blockIdx.y * 32;   // C_/32 = 8
    int tx = threadIdx.x, ty = threadIdx.y;
    tile[ty][tx] = tmp[((size_t)b * NBLK_ + n0 + ty) * C_ + c0 + tx];
    __syncthreads();
    out[((size_t)(b * C_ + c0 + ty)) * NBLK_ + n0 + tx] = tile[tx][ty];
}

extern "C" void kernel_launch(void* const* d_in, const int* in_sizes, int n_in,
                              void* d_out, int out_size, void* d_ws, size_t ws_size,
                              hipStream_t stream)
{
    const float* xyz_feats = (const float*)d_in[0];  // (B,C,M)
    const float* points    = (const float*)d_in[1];  // (B,N,3)
    const float* centers   = (const float*)d_in[2];  // (B,M,3)
    const float* Kmat      = (const float*)d_in[3];  // (3,3)

    float* out = (float*)d_out;

    // workspace layout (~21.7 MB)
    float*  XT       = (float*)d_ws;                         // 4 MB
    int4*   idP      = (int4*)(XT + (size_t)B_ * M_ * C_);   // 1 MB
    float4* wP       = (float4*)(idP + NT_);                 // 1 MB
    int4*   segs     = (int4*)(wP + NT_);                    // 228 KB
    float*  tmp      = (float*)(segs + MAXSEG_);             // 12.8 MB (zero rgn)
    float*  cnt      = tmp + (size_t)NBINS_ * C_;            // 784 KB
    int*    binCnt   = (int*)(cnt + (size_t)B_ * HW_);       // 50 KB
    int*    binFill  = binCnt + NBINS_;                      // 50 KB
    int*    segTotal = binFill + NBINS_;                     // 4 B
    int*    pixA     = segTotal + 1;                         // 256 KB
    int*    idA      = pixA + NT_;                           // 768 KB
    float*  wA       = (float*)(idA + 3 * NT_);              // 768 KB
    int*    binOff   = (int*)(wA + 3 * NT_);                 // 50 KB

    dim3 tb(32, 32);
    dim3 tg(C_ / 32, M_ / 32, B_);
    transpose_kernel<<<tg, tb, 0, stream>>>(xyz_feats, XT, tmp);

    dim3 bg(N_ / 256, B_);
    top3_kernel<<<bg, 1024, 0, stream>>>(points, centers, Kmat,
                                         pixA, idA, wA, cnt, binCnt);

    scan_kernel<<<1, 1024, 0, stream>>>(binCnt, binOff, segs, segTotal);

    pack_kernel<<<NT_ / 256, 256, 0, stream>>>(pixA, idA, wA, cnt,
                                               binOff, binFill, idP, wP);

    gather_kernel<<<MAXSEG_, 256, 0, stream>>>(XT, segs, segTotal,
                                               idP, wP, tmp);

    dim3 ug(NBLK_ / 32, C_ / 32, B_);
    untranspose_kernel<<<ug, tb, 0, stream>>>(tmp, out);
}